// Round 20
// baseline (564.013 us; speedup 1.0000x reference)
//
#include <hip/hip_runtime.h>
#include <hip/hip_bf16.h>
#include <math.h>

#define EPSV 1e-6f
#define INV_SCALE 0.04419417382415922f   // 1/sqrt(512)

typedef _Float16 half_t;
typedef __attribute__((ext_vector_type(8))) _Float16 half8;
typedef __attribute__((ext_vector_type(4))) _Float16 half4v;
typedef __attribute__((ext_vector_type(4))) float    f32x4;

__device__ __forceinline__ float ldf(const float* p)  { return *p; }
__device__ __forceinline__ float ldf(const half_t* p) { return (float)*p; }
__device__ __forceinline__ void  stf(float* p, float v)  { *p = v; }
__device__ __forceinline__ void  stf(half_t* p, float v) { *p = (half_t)v; }
__device__ __forceinline__ float frcp(float x) { return __builtin_amdgcn_rcpf(x); }
__device__ __forceinline__ half8 hz8() {
  half8 v = {(_Float16)0,(_Float16)0,(_Float16)0,(_Float16)0,
             (_Float16)0,(_Float16)0,(_Float16)0,(_Float16)0};
  return v;
}

// ---------------------------------------------------------------------------
// DPP wave-64 inclusive scans (validated rounds 11-19).
// ---------------------------------------------------------------------------
template<int CTRL, int RMASK>
__device__ __forceinline__ float dpp_add_step(float x) {
  int t = __builtin_amdgcn_update_dpp(0, __float_as_int(x), CTRL, RMASK, 0xf, true);
  return x + __int_as_float(t);
}
template<int CTRL, int RMASK>
__device__ __forceinline__ float dpp_mul_step(float x) {
  int t = __builtin_amdgcn_update_dpp(0x3f800000, __float_as_int(x), CTRL, RMASK, 0xf, false);
  return x * __int_as_float(t);
}
__device__ __forceinline__ float wave_iscan_add(float x) {
  x = dpp_add_step<0x111,0xf>(x);
  x = dpp_add_step<0x112,0xf>(x);
  x = dpp_add_step<0x114,0xf>(x);
  x = dpp_add_step<0x118,0xf>(x);
  x = dpp_add_step<0x142,0xa>(x);
  x = dpp_add_step<0x143,0xc>(x);
  return x;
}
__device__ __forceinline__ float wave_iscan_mul(float x) {
  x = dpp_mul_step<0x111,0xf>(x);
  x = dpp_mul_step<0x112,0xf>(x);
  x = dpp_mul_step<0x114,0xf>(x);
  x = dpp_mul_step<0x118,0xf>(x);
  x = dpp_mul_step<0x142,0xa>(x);
  x = dpp_mul_step<0x143,0xc>(x);
  return x;
}

// LDS-only barrier (skips the vmcnt(0) drain __syncthreads emits).
__device__ __forceinline__ void block_sync_lds() {
  asm volatile("s_waitcnt lgkmcnt(0)" ::: "memory");
  __builtin_amdgcn_s_barrier();
  asm volatile("" ::: "memory");
}

// Cross-wave prefix helpers over 4 wave-sums.
__device__ __forceinline__ float cross_sum4(const float* ws, int wid) {
  f32x4 a = *(const f32x4*)ws;
  float s = 0.f;
  #pragma unroll
  for (int j = 0; j < 4; j++) s += (wid > j) ? a[j] : 0.f;
  return s;
}
__device__ __forceinline__ float cross_prod4(const float* ws, int wid) {
  f32x4 a = *(const f32x4*)ws;
  float p = 1.f;
  #pragma unroll
  for (int j = 0; j < 4; j++) p *= (wid > j) ? a[j] : 1.f;
  return p;
}

// Bounded acquire-spin until flag reaches 24 (e_ma tiles per (chain, q-half)).
__device__ __forceinline__ void wait_flag24(unsigned int* f) {
  int guard = 0;
  while (__hip_atomic_load(f, __ATOMIC_ACQUIRE, __HIP_MEMORY_SCOPE_AGENT) < 24u) {
    __builtin_amdgcn_s_sleep(2);
    if (++guard > 200000) break;   // fail-safe: terminate (wrong) rather than hang
  }
}

// ---------------------------------------------------------------------------
// PREP (one dispatch): blocks 0-1279 five 512x512 weight transposes;
// 1280-13279 key->f16 copy; 13280 catbias; 13281-14304 zero cv_out (+flags).
// ---------------------------------------------------------------------------
__global__ __launch_bounds__(256)
void prep(const float* __restrict__ s0, half_t* __restrict__ d0,
          const float* __restrict__ s1, half_t* __restrict__ d1,
          const float* __restrict__ s2, half_t* __restrict__ d2,
          const float* __restrict__ s3, half_t* __restrict__ d3,
          const float* __restrict__ s4, half_t* __restrict__ d4,
          const float* __restrict__ key, half_t* __restrict__ keyh,
          const float* __restrict__ ba, const float* __restrict__ bb,
          const float* __restrict__ bc, const float* __restrict__ bd,
          float* __restrict__ cbq, float* __restrict__ cbk,
          float* __restrict__ cvz, unsigned int* __restrict__ flags)
{
  __shared__ float t[32][33];
  int blk = blockIdx.x;
  int tid = threadIdx.x;
  if (blk < 1280) {
    const float* W; half_t* WT;
    switch (blk >> 8) {
      case 0: W = s0; WT = d0; break;
      case 1: W = s1; WT = d1; break;
      case 2: W = s2; WT = d2; break;
      case 3: W = s3; WT = d3; break;
      default: W = s4; WT = d4; break;
    }
    int tile = blk & 255;
    int bx = tile & 15, by = tile >> 4;
    int r = tid >> 3, cq = tid & 7;
    float4 v = *(const float4*)&W[(size_t)(bx * 32 + r) * 512 + by * 32 + cq * 4];
    t[r][cq * 4 + 0] = v.x; t[r][cq * 4 + 1] = v.y;
    t[r][cq * 4 + 2] = v.z; t[r][cq * 4 + 3] = v.w;
    __syncthreads();
    half4v o;
    o[0] = (half_t)t[cq * 4 + 0][r];
    o[1] = (half_t)t[cq * 4 + 1][r];
    o[2] = (half_t)t[cq * 4 + 2][r];
    o[3] = (half_t)t[cq * 4 + 3][r];
    *(half4v*)&WT[(size_t)(by * 32 + r) * 512 + bx * 32 + cq * 4] = o;
  } else if (blk < 13280) {
    int i = (blk - 1280) * 256 + tid;
    if (i < 3072000) {
      f32x4 v = *(const f32x4*)&key[(size_t)i * 4];
      half4v h;
      h[0] = (half_t)v[0]; h[1] = (half_t)v[1]; h[2] = (half_t)v[2]; h[3] = (half_t)v[3];
      *(half4v*)&keyh[(size_t)i * 4] = h;
    }
  } else if (blk == 13280) {
    if (cbq != nullptr) {
      for (int i = tid; i < 512; i += 256) {
        cbq[i] = ba[i]; cbq[512 + i] = bb[i];
        cbk[i] = bc[i]; cbk[512 + i] = bd[i];
      }
    }
    if (flags != nullptr && tid < 64) flags[tid] = 0u;
  } else {
    int i = (blk - 13281) * 256 + tid;
    if (i < 262144) {
      f32x4 z = {0.f, 0.f, 0.f, 0.f};
      *(f32x4*)&cvz[(size_t)i * 4] = z;
    }
  }
}

// ---------------------------------------------------------------------------
// MFMA GEMM body. A operand fp32 (staged+cast) or f16 (direct 16B chunks).
// ---------------------------------------------------------------------------
struct GemmLds { half_t As[4][128][8]; half_t Bs[4][128][8]; };
struct __align__(16) ScanLds { float wsA[2][4]; float wsB[2][4]; };

__device__ __forceinline__
void stage_a(GemmLds& L, int tid, const float* __restrict__ A,
             int M, int Ke, int lda, int m0, int k0)
{
  #pragma unroll
  for (int i = 0; i < 4; i++) {
    int ch = tid + i * 256;
    int m = ch >> 3, cq = ch & 7, k = cq * 4;
    float4 v = make_float4(0.f, 0.f, 0.f, 0.f);
    if (m0 + m < M && k0 + k < Ke) v = *(const float4*)&A[(size_t)(m0 + m) * lda + k0 + k];
    half4v h;
    h[0] = (half_t)v.x; h[1] = (half_t)v.y; h[2] = (half_t)v.z; h[3] = (half_t)v.w;
    *(half4v*)&L.As[cq >> 1][m][(cq & 1) * 4] = h;
  }
}
__device__ __forceinline__
void stage_a(GemmLds& L, int tid, const half_t* __restrict__ A,
             int M, int Ke, int lda, int m0, int k0)
{
  #pragma unroll
  for (int i = 0; i < 2; i++) {
    int ch = tid + i * 256;
    int m = ch >> 2, kb = ch & 3;
    half8 v = hz8();
    if (m0 + m < M && k0 + kb * 8 < Ke)
      v = *(const half8*)&A[(size_t)(m0 + m) * lda + k0 + kb * 8];
    *(half8*)&L.As[kb][m][0] = v;
  }
}

template<int MODE, bool CT, bool ATOM, typename TA, typename TC>
__device__ __forceinline__
void mgemm_body(GemmLds& L, int tid, int bxx, int byy, int bzz,
                const TA* __restrict__ A, const half_t* __restrict__ BT,
                TC* __restrict__ C, int M, int N, int Kd,
                int lda, int ldb, int ldc, int hdiv, int kdiv, int kc,
                long long sAb, long long sAh, long long sBb, long long sBh,
                long long sCb, long long sCh,
                const float* __restrict__ bias, const float* __restrict__ rvec)
{
  int ks = bzz % kdiv; int zz = bzz / kdiv;
  int bz = zz / hdiv, hz = zz - bz * hdiv;
  A  += (size_t)bz * sAb + (size_t)hz * sAh + (size_t)ks * kc;
  BT += (size_t)bz * sBb + (size_t)hz * sBh + (size_t)ks * kc;
  C  += (size_t)bz * sCb + (size_t)hz * sCh;
  int Ke = Kd - ks * kc; if (Ke > kc) Ke = kc;

  int lane = tid & 63, wid = tid >> 6;
  int wm = wid >> 1, wn = wid & 1;
  int m0 = byy * 128, n0 = bxx * 128;

  f32x4 acc[4][4] = {};

  for (int k0 = 0; k0 < Ke; k0 += 32) {
    stage_a(L, tid, A, M, Ke, lda, m0, k0);
    #pragma unroll
    for (int i = 0; i < 2; i++) {            // B: 128x32 f16
      int ch = tid + i * 256;
      int n = ch >> 2, kb = ch & 3;
      half8 v = hz8();
      if (n0 + n < N && k0 + kb * 8 < Ke)
        v = *(const half8*)&BT[(size_t)(n0 + n) * ldb + k0 + kb * 8];
      *(half8*)&L.Bs[kb][n][0] = v;
    }
    __syncthreads();
    int kb = lane >> 4, r = lane & 15;
    half8 af[4], bfv[4];
    #pragma unroll
    for (int mi = 0; mi < 4; mi++) af[mi]  = *(const half8*)&L.As[kb][wm * 64 + mi * 16 + r][0];
    #pragma unroll
    for (int ni = 0; ni < 4; ni++) bfv[ni] = *(const half8*)&L.Bs[kb][wn * 64 + ni * 16 + r][0];
    #pragma unroll
    for (int mi = 0; mi < 4; mi++)
      #pragma unroll
      for (int ni = 0; ni < 4; ni++)
        acc[mi][ni] = __builtin_amdgcn_mfma_f32_16x16x32_f16(af[mi], bfv[ni], acc[mi][ni], 0, 0, 0);
    __syncthreads();
  }

  float radd = (MODE == 1) ? rvec[hz] : 0.f;
  int r = lane & 15, g = lane >> 4;
  #pragma unroll
  for (int mi = 0; mi < 4; mi++) {
    #pragma unroll
    for (int ni = 0; ni < 4; ni++) {
      int col = n0 + wn * 64 + ni * 16 + r;
      if (col >= N) continue;
      float bv = (MODE == 0) ? bias[col] : 0.f;
      if (CT) {
        int row0 = m0 + wm * 64 + mi * 16 + g * 4;
        if (row0 + 3 < M) {
          half4v o;
          #pragma unroll
          for (int j = 0; j < 4; j++) o[j] = (half_t)(acc[mi][ni][j] + bv);
          *(half4v*)&((half_t*)C)[(size_t)col * ldc + row0] = o;
        }
      } else {
        #pragma unroll
        for (int j = 0; j < 4; j++) {
          int row = m0 + wm * 64 + mi * 16 + g * 4 + j;
          if (row >= M) continue;
          float v = acc[mi][ni][j];
          if (MODE == 0)      v += bv;
          else if (MODE == 1) v = frcp(1.f + expf(-(v * INV_SCALE + radd)));
          else if (MODE == 2) v *= INV_SCALE;
          if (ATOM) atomicAdd((float*)&C[(size_t)row * ldc + col], v);
          else      stf(&C[(size_t)row * ldc + col], v);
        }
      }
    }
  }
}

template<int MODE, bool CT, bool ATOM, typename TA, typename TC>
__global__ __launch_bounds__(256)
void mgemm(const TA* __restrict__ A, const half_t* __restrict__ BT,
           TC* __restrict__ C, int M, int N, int Kd,
           int lda, int ldb, int ldc, int hdiv, int kdiv, int kc,
           long long sAb, long long sAh, long long sBb, long long sBh,
           long long sCb, long long sCh,
           const float* __restrict__ bias, const float* __restrict__ rvec)
{
  __shared__ GemmLds L;
  mgemm_body<MODE,CT,ATOM,TA,TC>(L, threadIdx.x, blockIdx.x, blockIdx.y, blockIdx.z,
                                 A, BT, C, M, N, Kd, lda, ldb, ldc, hdiv, kdiv, kc,
                                 sAb, sAh, sBb, sBh, sCb, sCh, bias, rvec);
}

// ---------------------------------------------------------------------------
// qall + kall merged (v3): blocks 0-127 = qall (2048x1024, A fp32),
// blocks 128-1631 = kall (24000x1024, A f16).
// ---------------------------------------------------------------------------
__global__ __launch_bounds__(256)
void qk_fused(const float* __restrict__ query, const half_t* __restrict__ keyh,
              const half_t* __restrict__ wt_q, const half_t* __restrict__ wt_k,
              half_t* __restrict__ qbuf, half_t* __restrict__ kbuf2,
              const float* __restrict__ cb_q, const float* __restrict__ cb_k)
{
  __shared__ GemmLds L;
  int blk = blockIdx.x;
  if (blk < 128) {
    mgemm_body<0,false,false,float,half_t>(L, threadIdx.x, blk & 7, blk >> 3, 0,
        query, wt_q, qbuf, 2048, 1024, 512, 512, 512, 1024, 1, 1, 512,
        0, 0, 0, 0, 0, 0, cb_q, nullptr);
  } else {
    int vb = blk - 128;
    mgemm_body<0,false,false,half_t,half_t>(L, threadIdx.x, vb % 8, vb / 8, 0,
        keyh, wt_k, kbuf2, 24000, 1024, 512, 512, 512, 1024, 1, 1, 512,
        0, 0, 0, 0, 0, 0, cb_k, nullptr);
  }
}

// ---------------------------------------------------------------------------
// FUSED (256 threads, launch_bounds(256,1)):
// EMA=true (v3): 0-31 scan | 32-1567 e_ma shells (flag-signaling) |
//                1568-1951 u | 1952-2703 vT.
// EMA=false (v1): 0-31 scan (no waits) | 32-415 u.
// Scan: 8-deep software-pipelined p prefetch; acquire-spin on e_ma flags.
// ---------------------------------------------------------------------------
union MidLds { GemmLds g; ScanLds s; };

template<bool EMA>
__global__ __launch_bounds__(256, 1)
void fused_mid(half_t* __restrict__ p16, float* __restrict__ alpha_slot,
               const half_t* __restrict__ qa, const half_t* __restrict__ kb,
               int lda_u, int ldb_u, long long sAb_u, long long sBb_u,
               float* __restrict__ u_buf,
               const half_t* __restrict__ keyh, const half_t* __restrict__ wt_v,
               half_t* __restrict__ vtbuf, const float* __restrict__ b_value,
               const half_t* __restrict__ qfull, const half_t* __restrict__ kfull,
               const float* __restrict__ rvec, unsigned int* __restrict__ flags)
{
  __shared__ MidLds lds;
  int blk = blockIdx.x;
  int tid = threadIdx.x;

  if (blk >= 32) {
    if (EMA && blk < 1568) {             // ---- e_ma shells: vb in [0,1536) ----
      int vb = blk - 32;
      int bx = vb % 24; int t = vb / 24;
      int by = t & 1;   int bz = t >> 1;
      mgemm_body<1,false,false,half_t,half_t>(lds.g, tid, bx, by, bz, qfull, kfull, p16,
          256, 3000, 128, 1024, 1024, 3000, 4, 1, 128,
          262144, 128, 3072000, 128, 3072000, 768000, nullptr, rvec);
      __syncthreads();                   // vmcnt(0) drain: all tile stores done
      if (tid == 0) {
        __threadfence();                 // device-scope visibility for p16
        __hip_atomic_fetch_add(&flags[bz * 2 + by], 1u, __ATOMIC_RELEASE, __HIP_MEMORY_SCOPE_AGENT);
      }
      return;
    }
    int ubase = EMA ? 1568 : 32;
    int vbase = EMA ? 1952 : 416;
    if (blk < vbase) {                   // ---- u GEMM: vb in [0,384) ----
      int vb = blk - ubase;
      int bx = vb % 24; int t = vb / 24;
      int by = t & 1;   int bz = t >> 1;
      mgemm_body<2,false,false,half_t,float>(lds.g, tid, bx, by, bz, qa, kb, u_buf,
          256, 3000, 512, lda_u, ldb_u, 3000, 1, 1, 512,
          sAb_u, 0, sBb_u, 0, 768000, 0, nullptr, nullptr);
    } else {                             // ---- vT proj: vb in [0,752) ----
      int vb = blk - vbase;
      int bx = vb & 3; int by = vb >> 2;
      mgemm_body<0,true,false,half_t,half_t>(lds.g, tid, bx, by, 0, keyh, wt_v, vtbuf,
          24000, 512, 512, 512, 512, 24000, 1, 1, 512,
          0, 0, 0, 0, 0, 0, b_value, nullptr);
    }
    return;
  }

  // ---- scan for chain blk: 256 thr x 12 elems (3000 = 250x12) ----
  if (EMA) {                             // wait for this chain's q-half 0
    if (tid == 0) wait_flag24(&flags[blk * 2]);
    block_sync_lds();
  }
  __builtin_amdgcn_s_setprio(1);
  float (&wsA)[2][4] = lds.s.wsA;
  float (&wsB)[2][4] = lds.s.wsB;
  int lane = tid & 63, wid = tid >> 6;
  int k0 = tid * 12;
  size_t zbase = (size_t)blk * 768000;   // 256*3000
  const half_t* prow = p16 + zbase;

  half4v ph0[3], pb0[3], pb1[3], pb2[3], pb3[3], pb4[3], pb5[3], pb6[3], pb7[3];
  #pragma unroll
  for (int j = 0; j < 3; j++) {
    int k = k0 + j * 4;
    half4v z = {(_Float16)0,(_Float16)0,(_Float16)0,(_Float16)0};
    bool ok = (k + 4 <= 3000);
    ph0[j] = ok ? *(const half4v*)&prow[k]         : z;
    pb0[j] = ok ? *(const half4v*)&prow[3000 + k]  : z;
    pb1[j] = ok ? *(const half4v*)&prow[6000 + k]  : z;
    pb2[j] = ok ? *(const half4v*)&prow[9000 + k]  : z;
    pb3[j] = ok ? *(const half4v*)&prow[12000 + k] : z;
    pb4[j] = ok ? *(const half4v*)&prow[15000 + k] : z;
    pb5[j] = ok ? *(const half4v*)&prow[18000 + k] : z;
    pb6[j] = ok ? *(const half4v*)&prow[21000 + k] : z;
    pb7[j] = ok ? *(const half4v*)&prow[24000 + k] : z;
  }

  float a_prev[12];
  #pragma unroll
  for (int c = 0; c < 12; c++) a_prev[c] = 0.f;
  if (tid == 0) a_prev[0] = 1.f;

  float cpv[12], w[12];
  { // prologue: cp row 0 (multiplicative DPP scan), w = p0*cp0
    float l[12], m = 1.f;
    float p0f[12];
    #pragma unroll
    for (int c = 0; c < 12; c++) {
      p0f[c] = (float)ph0[c >> 2][c & 3];
      l[c] = m;
      m *= fmaxf(1.f - p0f[c], EPSV);
    }
    float incl = wave_iscan_mul(m);
    if (lane == 63) wsA[1][wid] = incl;
    float exclw = incl * frcp(fmaxf(m, 1e-30f));
    block_sync_lds();
    float base = exclw * cross_prod4(&wsA[1][0], wid);
    #pragma unroll
    for (int c = 0; c < 12; c++) { cpv[c] = base * l[c]; w[c] = p0f[c] * cpv[c]; }
  }

#define SCAN_STEP(I, BUF)                                                     \
  {                                                                           \
    int par = (I) & 1;                                                        \
    float t_[12], s2 = 0.f;                                                   \
    _Pragma("unroll")                                                         \
    for (int c = 0; c < 12; c++) {                                            \
      s2 = fmaf(a_prev[c], frcp(fmaxf(cpv[c], EPSV)), s2);                    \
      t_[c] = s2;                                                             \
    }                                                                         \
    float incl2 = wave_iscan_add(s2);                                         \
    if (lane == 63) wsB[par][wid] = incl2;                                    \
    float excl2 = incl2 - s2;                                                 \
    float pnf[12], l_[12], m_ = 1.f;                                          \
    _Pragma("unroll")                                                         \
    for (int c = 0; c < 12; c++) {                                            \
      pnf[c] = (float)BUF[c >> 2][c & 3];                                     \
      l_[c] = m_;                                                             \
      m_ *= fmaxf(1.f - pnf[c], EPSV);                                        \
    }                                                                         \
    float incl1 = wave_iscan_mul(m_);                                         \
    if (lane == 63) wsA[par][wid] = incl1;                                    \
    float excl1 = incl1 * frcp(fmaxf(m_, 1e-30f));                            \
    block_sync_lds();                                                         \
    if ((I) + 9 <= 255) {                                                     \
      const half_t* nrow = prow + (size_t)((I) + 9) * 3000;                   \
      _Pragma("unroll")                                                       \
      for (int j = 0; j < 3; j++) {                                           \
        int k = k0 + j * 4;                                                   \
        if (k + 4 <= 3000) BUF[j] = *(const half4v*)&nrow[k];                 \
      }                                                                       \
    }                                                                         \
    __builtin_amdgcn_sched_barrier(0);                                        \
    float off = excl2 + cross_sum4(&wsB[par][0], wid);                        \
    size_t rbase = zbase + (size_t)(I) * 3000;                                \
    _Pragma("unroll")                                                         \
    for (int q4 = 0; q4 < 3; q4++) {                                          \
      f32x4 o;                                                                \
      _Pragma("unroll")                                                       \
      for (int j = 0; j < 4; j++) {                                           \
        int c = q4 * 4 + j;                                                   \
        float an = w[c] * (off + t_[c]);                                      \
        a_prev[c] = an;                                                       \
        o[j] = an;                                                            \
      }                                                                       \
      int k = k0 + q4 * 4;                                                    \
      if (k + 4 <= 3000) *(f32x4*)&alpha_slot[rbase + k] = o;                 \
    }                                                                         \
    float base1 = excl1 * cross_prod4(&wsA[par][0], wid);                     \
    _Pragma("unroll")                                                         \
    for (int c = 0; c < 12; c++) { cpv[c] = base1 * l_[c]; w[c] = pnf[c] * cpv[c]; } \
  }

  for (int i = 0; i < 256; i += 8) {
    if (EMA && i == 112) {               // step 119 prefetches row 128: need q-half 1
      if (tid == 0) wait_flag24(&flags[blk * 2 + 1]);
      block_sync_lds();
    }
    SCAN_STEP(i,     pb0);
    SCAN_STEP(i + 1, pb1);
    SCAN_STEP(i + 2, pb2);
    SCAN_STEP(i + 3, pb3);
    SCAN_STEP(i + 4, pb4);
    SCAN_STEP(i + 5, pb5);
    SCAN_STEP(i + 6, pb6);
    SCAN_STEP(i + 7, pb7);
  }
#undef SCAN_STEP
}

// ---------------------------------------------------------------------------
// Chunkwise beta — sliding-window form (round 19, unchanged).
// ---------------------------------------------------------------------------
__global__ __launch_bounds__(256)
void beta_kernel(const float* __restrict__ ubuf, const float* __restrict__ alpha_slot,
                 float* __restrict__ beta_slot)
{
  __shared__ __align__(16) float se[3008];
  __shared__ __align__(16) float dn[3008];
  __shared__ __align__(16) float tt[3040];
  __shared__ float red[4];
  int bq = blockIdx.x;
  int b = bq >> 8, q = bq & 255;
  int tid = threadIdx.x;
  int lane = tid & 63, wid = tid >> 6;
  int k0 = tid * 12;
  bool act = (k0 < 3000);
  const float* urow = ubuf + (size_t)bq * 3000;
  float lmax = -3.0e38f;
  for (int c = tid; c < 750; c += 256) {
    f32x4 v = *(const f32x4*)&urow[c * 4];
    *(f32x4*)&se[c * 4] = v;
    lmax = fmaxf(lmax, fmaxf(fmaxf(v[0], v[1]), fmaxf(v[2], v[3])));
  }
  #pragma unroll
  for (int d = 32; d > 0; d >>= 1) lmax = fmaxf(lmax, __shfl_xor(lmax, d));
  if (lane == 0) red[wid] = lmax;
  __syncthreads();
  float umax = fmaxf(fmaxf(red[0], red[1]), fmaxf(red[2], red[3]));
  for (int c = tid; c < 750; c += 256) {
    f32x4 v = *(const f32x4*)&se[c * 4];
    #pragma unroll
    for (int j = 0; j < 4; j++) v[j] = fmaxf(expf(v[j] - umax), 1e-5f);
    *(f32x4*)&se[c * 4] = v;
  }
  if (tid < 40) tt[3000 + tid] = 0.f;
  __syncthreads();
  if (act) {
    float sb[27];
    #pragma unroll
    for (int j = 0; j < 27; j++) {
      int idx = k0 - 15 + j;
      sb[j] = (idx >= 0) ? se[idx] : 0.f;
    }
    float wsum = 0.f;
    #pragma unroll
    for (int j = 0; j < 16; j++) wsum += sb[j];
    dn[k0] = wsum;
    #pragma unroll
    for (int j = 1; j < 12; j++) {
      wsum += sb[15 + j] - sb[j - 1];
      dn[k0 + j] = wsum;
    }
  }
  __syncthreads();
  for (int h = 0; h < 4; h++) {
    const float* arow = alpha_slot + ((size_t)((b * 4 + h) * 256 + q)) * 3000;
    for (int c = tid; c < 750; c += 256) {
      f32x4 a = *(const f32x4*)&arow[c * 4];
      f32x4 d = *(const f32x4*)&dn[c * 4];
      f32x4 o;
      #pragma unroll
      for (int j = 0; j < 4; j++) o[j] = a[j] * frcp(d[j]);
      *(f32x4*)&tt[c * 4] = o;
    }
    __syncthreads();
    float* brow = beta_slot + ((size_t)((b * 4 + h) * 256 + q)) * 3000;
    if (act) {
      float tb[28];
      #pragma unroll
      for (int j = 0; j < 28; j++) tb[j] = tt[k0 + j];
      float wv = 0.f;
      #pragma unroll
      for (int j = 0; j < 16; j++) wv += tb[j];
      float outv[12];
      outv[0] = se[k0] * wv;
      #pragma unroll
      for (int j = 1; j < 12; j++) {
        wv += tb[15 + j] - tb[j - 1];
        outv[j] = se[k0 + j] * wv;
      }
      #pragma unroll
      for (int q4 = 0; q4 < 3; q4++) {
        f32x4 o;
        #pragma unroll
        for (int j = 0; j < 4; j++) o[j] = outv[q4 * 4 + j];
        *(f32x4*)&brow[k0 + q4 * 4] = o;
      }
    }
    __syncthreads();
  }
}

// ---------------------------------------------------------------------------
extern "C" void kernel_launch(void* const* d_in, const int* in_sizes, int n_in,
                              void* d_out, int out_size, void* d_ws, size_t ws_size,
                              hipStream_t stream)
{
  const float* key        = (const float*)d_in[0];
  const float* query      = (const float*)d_in[1];
  const float* w_key_ma   = (const float*)d_in[2];
  const float* b_key_ma   = (const float*)d_in[3];
  const float* w_query_ma = (const float*)d_in[4];
  const float* b_query_ma = (const float*)d_in[5];
  const float* rvec       = (const float*)d_in[6];
  const float* w_key_ca   = (const float*)d_in[7];
  const float* b_key_ca   = (const float*)d_in[8];
  const float* w_query_ca = (const float*)d_in[9];
  const float* b_query_ca = (const float*)d_in[10];
  const float* w_value    = (const float*)d_in[11];
  const float* b_value    = (const float*)d_in[12];

  // Outputs FP32: cv | alpha | beta, flat.
  float* out       = (float*)d_out;
  float* cv_out    = out;                                  // (8,256,512)
  float* alpha_out = out + (size_t)1048576;                // (8,4,256,3000)
  float* beta_out  = alpha_out + (size_t)24576000;         // (8,4,256,3000)
  half_t* p16      = (half_t*)beta_out;                    // p_choose fp16 (first half)
  half_t* keyh     = (half_t*)(beta_out + 12288000);       // key f16 (second half; dead before beta)

  dim3 blk(256);
  bool v3 = ws_size >= (size_t)109322240;

  if (v3) {
    // v3 layout: kbuf2[24000][1024] f16 | qbuf[2048][1024] f16 | u f32 | vtbuf | wts | cb+flags
    half_t* kbuf2 = (half_t*)d_ws;
    half_t* qbuf  = (half_t*)((char*)d_ws + 49152000);
    float*  u_buf = (float*)((char*)d_ws + 57540608);
    half_t* vtbuf = (half_t*)((char*)d_ws + 82116608);
    half_t* wt_q  = (half_t*)((char*)d_ws + 106692608);   // [1024][512]
    half_t* wt_k  = (half_t*)((char*)d_ws + 107741184);   // [1024][512]
    half_t* wt_v  = (half_t*)((char*)d_ws + 108789760);
    float*  cb_q  = (float*)((char*)d_ws + 109314048);
    unsigned int* flags = (unsigned int*)((char*)d_ws + 109316096);  // 64 u32, in cb slack
    float*  cb_k  = (float*)((char*)d_ws + 109318144);

    prep<<<dim3(14305), blk, 0, stream>>>(
        w_query_ma, wt_q, w_query_ca, wt_q + 262144,
        w_key_ma,   wt_k, w_key_ca,   wt_k + 262144,
        w_value,    wt_v, key, keyh,
        b_query_ma, b_query_ca, b_key_ma, b_key_ca, cb_q, cb_k,
        cv_out, flags);

    qk_fused<<<dim3(1632), blk, 0, stream>>>(query, keyh, wt_q, wt_k, qbuf, kbuf2, cb_q, cb_k);

    // FUSED: e_ma shells (flag-signaled) + scan + u + vT
    fused_mid<true><<<dim3(2704), blk, 0, stream>>>(p16, alpha_out,
        qbuf + 512, kbuf2 + 512, 1024, 1024, 262144, 3072000,
        u_buf, keyh, wt_v, vtbuf, b_value,
        qbuf, kbuf2, rvec, flags);

    beta_kernel<<<dim3(2048), blk, 0, stream>>>(u_buf, alpha_out, beta_out);

    mgemm<3,false,true,float,float><<<dim3(1,2,256), blk, 0, stream>>>(beta_out, vtbuf, cv_out, 256,128,3000, 3000,24000,512, 4,8,384,
        3072000,768000, 3000,3072000, 131072,128, nullptr, nullptr);
  } else {
    // v1 fallback: kbuf | qbuf | u | 5x wt. 55.97MB.
    if (ws_size < (size_t)55967744) return;
    half_t* kbuf   = (half_t*)d_ws;
    half_t* qbuf   = (half_t*)((char*)d_ws + 24576000);
    float*  u_buf  = (float*)((char*)d_ws + 28770304);
    half_t* wt_qma = (half_t*)((char*)d_ws + 53346304);
    half_t* wt_kma = (half_t*)((char*)d_ws + 53870592);
    half_t* wt_qca = (half_t*)((char*)d_ws + 54394880);
    half_t* wt_kca = (half_t*)((char*)d_ws + 54919168);
    half_t* wt_v   = (half_t*)((char*)d_ws + 55443456);

    prep<<<dim3(14305), blk, 0, stream>>>(
        w_query_ma, wt_qma, w_query_ca, wt_qca,
        w_key_ma,   wt_kma, w_key_ca,   wt_kca,
        w_value,    wt_v, key, keyh,
        nullptr, nullptr, nullptr, nullptr, nullptr, nullptr,
        cv_out, nullptr);

    mgemm<0,false,false,float ,half_t><<<dim3(4,16,1),  blk, 0, stream>>>(query, wt_qma, qbuf, 2048, 512, 512, 512,512,512, 1,1,512, 0,0,0,0,0,0, b_query_ma, nullptr);
    mgemm<0,false,false,half_t,half_t><<<dim3(4,188,1), blk, 0, stream>>>(keyh,  wt_kma, kbuf, 24000,512, 512, 512,512,512, 1,1,512, 0,0,0,0,0,0, b_key_ma,   nullptr);
    mgemm<1,false,false,half_t,half_t><<<dim3(24,2,32), blk, 0, stream>>>(qbuf,  kbuf, p16, 256,3000, 128, 512,512,3000, 4,1,128,
        131072,128, 1536000,128, 3072000,768000, nullptr, rvec);

    mgemm<0,false,false,float ,half_t><<<dim3(4,16,1),  blk, 0, stream>>>(query, wt_qca, qbuf, 2048, 512, 512, 512,512,512, 1,1,512, 0,0,0,0,0,0, b_query_ca, nullptr);
    mgemm<0,false,false,half_t,half_t><<<dim3(4,188,1), blk, 0, stream>>>(keyh,  wt_kca, kbuf, 24000,512, 512, 512,512,512, 1,1,512, 0,0,0,0,0,0, b_key_ca,   nullptr);

    fused_mid<false><<<dim3(416), blk, 0, stream>>>(p16, alpha_out,
        qbuf, kbuf, 512, 512, 131072, 1536000,
        u_buf, keyh, wt_v, kbuf, b_value,
        nullptr, nullptr, nullptr, nullptr);

    mgemm<0,true,false,half_t,half_t><<<dim3(4,188,1), blk, 0, stream>>>(keyh, wt_v, kbuf, 24000,512, 512, 512,512,24000, 1,1,512, 0,0,0,0,0,0, b_value, nullptr);

    beta_kernel<<<dim3(2048), blk, 0, stream>>>(u_buf, alpha_out, beta_out);

    mgemm<3,false,true,float,float><<<dim3(1,2,256), blk, 0, stream>>>(beta_out, kbuf, cv_out, 256,128,3000, 3000,24000,512, 4,8,384,
        3072000,768000, 3000,3072000, 131072,128, nullptr, nullptr);
  }
}

// Round 21
// 423.247 us; speedup vs baseline: 1.3326x; 1.3326x over previous
//
#include <hip/hip_runtime.h>
#include <hip/hip_bf16.h>
#include <math.h>

#define EPSV 1e-6f
#define INV_SCALE 0.04419417382415922f   // 1/sqrt(512)

typedef _Float16 half_t;
typedef __attribute__((ext_vector_type(8))) _Float16 half8;
typedef __attribute__((ext_vector_type(4))) _Float16 half4v;
typedef __attribute__((ext_vector_type(4))) float    f32x4;

__device__ __forceinline__ float ldf(const float* p)  { return *p; }
__device__ __forceinline__ float ldf(const half_t* p) { return (float)*p; }
__device__ __forceinline__ void  stf(float* p, float v)  { *p = v; }
__device__ __forceinline__ void  stf(half_t* p, float v) { *p = (half_t)v; }
__device__ __forceinline__ float frcp(float x) { return __builtin_amdgcn_rcpf(x); }
__device__ __forceinline__ half8 hz8() {
  half8 v = {(_Float16)0,(_Float16)0,(_Float16)0,(_Float16)0,
             (_Float16)0,(_Float16)0,(_Float16)0,(_Float16)0};
  return v;
}

// ---------------------------------------------------------------------------
// DPP wave-64 inclusive scans (validated rounds 11-19).
// ---------------------------------------------------------------------------
template<int CTRL, int RMASK>
__device__ __forceinline__ float dpp_add_step(float x) {
  int t = __builtin_amdgcn_update_dpp(0, __float_as_int(x), CTRL, RMASK, 0xf, true);
  return x + __int_as_float(t);
}
template<int CTRL, int RMASK>
__device__ __forceinline__ float dpp_mul_step(float x) {
  int t = __builtin_amdgcn_update_dpp(0x3f800000, __float_as_int(x), CTRL, RMASK, 0xf, false);
  return x * __int_as_float(t);
}
__device__ __forceinline__ float wave_iscan_add(float x) {
  x = dpp_add_step<0x111,0xf>(x);
  x = dpp_add_step<0x112,0xf>(x);
  x = dpp_add_step<0x114,0xf>(x);
  x = dpp_add_step<0x118,0xf>(x);
  x = dpp_add_step<0x142,0xa>(x);
  x = dpp_add_step<0x143,0xc>(x);
  return x;
}
__device__ __forceinline__ float wave_iscan_mul(float x) {
  x = dpp_mul_step<0x111,0xf>(x);
  x = dpp_mul_step<0x112,0xf>(x);
  x = dpp_mul_step<0x114,0xf>(x);
  x = dpp_mul_step<0x118,0xf>(x);
  x = dpp_mul_step<0x142,0xa>(x);
  x = dpp_mul_step<0x143,0xc>(x);
  return x;
}

// LDS-only barrier (skips the vmcnt(0) drain __syncthreads emits).
__device__ __forceinline__ void block_sync_lds() {
  asm volatile("s_waitcnt lgkmcnt(0)" ::: "memory");
  __builtin_amdgcn_s_barrier();
  asm volatile("" ::: "memory");
}

// Cross-wave prefix helpers over 4 wave-sums.
__device__ __forceinline__ float cross_sum4(const float* ws, int wid) {
  f32x4 a = *(const f32x4*)ws;
  float s = 0.f;
  #pragma unroll
  for (int j = 0; j < 4; j++) s += (wid > j) ? a[j] : 0.f;
  return s;
}
__device__ __forceinline__ float cross_prod4(const float* ws, int wid) {
  f32x4 a = *(const f32x4*)ws;
  float p = 1.f;
  #pragma unroll
  for (int j = 0; j < 4; j++) p *= (wid > j) ? a[j] : 1.f;
  return p;
}

// ---------------------------------------------------------------------------
// PREP (one dispatch): blocks 0-1279 five 512x512 weight transposes;
// 1280-13279 key->f16 copy; 13280 catbias; 13281-14304 zero cv_out.
// ---------------------------------------------------------------------------
__global__ __launch_bounds__(256)
void prep(const float* __restrict__ s0, half_t* __restrict__ d0,
          const float* __restrict__ s1, half_t* __restrict__ d1,
          const float* __restrict__ s2, half_t* __restrict__ d2,
          const float* __restrict__ s3, half_t* __restrict__ d3,
          const float* __restrict__ s4, half_t* __restrict__ d4,
          const float* __restrict__ key, half_t* __restrict__ keyh,
          const float* __restrict__ ba, const float* __restrict__ bb,
          const float* __restrict__ bc, const float* __restrict__ bd,
          float* __restrict__ cbq, float* __restrict__ cbk,
          float* __restrict__ cvz)
{
  __shared__ float t[32][33];
  int blk = blockIdx.x;
  int tid = threadIdx.x;
  if (blk < 1280) {
    const float* W; half_t* WT;
    switch (blk >> 8) {
      case 0: W = s0; WT = d0; break;
      case 1: W = s1; WT = d1; break;
      case 2: W = s2; WT = d2; break;
      case 3: W = s3; WT = d3; break;
      default: W = s4; WT = d4; break;
    }
    int tile = blk & 255;
    int bx = tile & 15, by = tile >> 4;
    int r = tid >> 3, cq = tid & 7;
    float4 v = *(const float4*)&W[(size_t)(bx * 32 + r) * 512 + by * 32 + cq * 4];
    t[r][cq * 4 + 0] = v.x; t[r][cq * 4 + 1] = v.y;
    t[r][cq * 4 + 2] = v.z; t[r][cq * 4 + 3] = v.w;
    __syncthreads();
    half4v o;
    o[0] = (half_t)t[cq * 4 + 0][r];
    o[1] = (half_t)t[cq * 4 + 1][r];
    o[2] = (half_t)t[cq * 4 + 2][r];
    o[3] = (half_t)t[cq * 4 + 3][r];
    *(half4v*)&WT[(size_t)(by * 32 + r) * 512 + bx * 32 + cq * 4] = o;
  } else if (blk < 13280) {
    int i = (blk - 1280) * 256 + tid;
    if (i < 3072000) {
      f32x4 v = *(const f32x4*)&key[(size_t)i * 4];
      half4v h;
      h[0] = (half_t)v[0]; h[1] = (half_t)v[1]; h[2] = (half_t)v[2]; h[3] = (half_t)v[3];
      *(half4v*)&keyh[(size_t)i * 4] = h;
    }
  } else if (blk == 13280) {
    if (cbq != nullptr) {
      for (int i = tid; i < 512; i += 256) {
        cbq[i] = ba[i]; cbq[512 + i] = bb[i];
        cbk[i] = bc[i]; cbk[512 + i] = bd[i];
      }
    }
  } else {
    int i = (blk - 13281) * 256 + tid;
    if (i < 262144) {
      f32x4 z = {0.f, 0.f, 0.f, 0.f};
      *(f32x4*)&cvz[(size_t)i * 4] = z;
    }
  }
}

// ---------------------------------------------------------------------------
// MFMA GEMM body. A operand fp32 (staged+cast) or f16 (direct 16B chunks).
// ---------------------------------------------------------------------------
struct GemmLds { half_t As[4][128][8]; half_t Bs[4][128][8]; };
struct __align__(16) ScanLds { float wsA[2][4]; float wsB[2][4]; };

__device__ __forceinline__
void stage_a(GemmLds& L, int tid, const float* __restrict__ A,
             int M, int Ke, int lda, int m0, int k0)
{
  #pragma unroll
  for (int i = 0; i < 4; i++) {
    int ch = tid + i * 256;
    int m = ch >> 3, cq = ch & 7, k = cq * 4;
    float4 v = make_float4(0.f, 0.f, 0.f, 0.f);
    if (m0 + m < M && k0 + k < Ke) v = *(const float4*)&A[(size_t)(m0 + m) * lda + k0 + k];
    half4v h;
    h[0] = (half_t)v.x; h[1] = (half_t)v.y; h[2] = (half_t)v.z; h[3] = (half_t)v.w;
    *(half4v*)&L.As[cq >> 1][m][(cq & 1) * 4] = h;
  }
}
__device__ __forceinline__
void stage_a(GemmLds& L, int tid, const half_t* __restrict__ A,
             int M, int Ke, int lda, int m0, int k0)
{
  #pragma unroll
  for (int i = 0; i < 2; i++) {
    int ch = tid + i * 256;
    int m = ch >> 2, kb = ch & 3;
    half8 v = hz8();
    if (m0 + m < M && k0 + kb * 8 < Ke)
      v = *(const half8*)&A[(size_t)(m0 + m) * lda + k0 + kb * 8];
    *(half8*)&L.As[kb][m][0] = v;
  }
}

template<int MODE, bool CT, bool ATOM, typename TA, typename TC>
__device__ __forceinline__
void mgemm_body(GemmLds& L, int tid, int bxx, int byy, int bzz,
                const TA* __restrict__ A, const half_t* __restrict__ BT,
                TC* __restrict__ C, int M, int N, int Kd,
                int lda, int ldb, int ldc, int hdiv, int kdiv, int kc,
                long long sAb, long long sAh, long long sBb, long long sBh,
                long long sCb, long long sCh,
                const float* __restrict__ bias, const float* __restrict__ rvec)
{
  int ks = bzz % kdiv; int zz = bzz / kdiv;
  int bz = zz / hdiv, hz = zz - bz * hdiv;
  A  += (size_t)bz * sAb + (size_t)hz * sAh + (size_t)ks * kc;
  BT += (size_t)bz * sBb + (size_t)hz * sBh + (size_t)ks * kc;
  C  += (size_t)bz * sCb + (size_t)hz * sCh;
  int Ke = Kd - ks * kc; if (Ke > kc) Ke = kc;

  int lane = tid & 63, wid = tid >> 6;
  int wm = wid >> 1, wn = wid & 1;
  int m0 = byy * 128, n0 = bxx * 128;

  f32x4 acc[4][4] = {};

  for (int k0 = 0; k0 < Ke; k0 += 32) {
    stage_a(L, tid, A, M, Ke, lda, m0, k0);
    #pragma unroll
    for (int i = 0; i < 2; i++) {            // B: 128x32 f16
      int ch = tid + i * 256;
      int n = ch >> 2, kb = ch & 3;
      half8 v = hz8();
      if (n0 + n < N && k0 + kb * 8 < Ke)
        v = *(const half8*)&BT[(size_t)(n0 + n) * ldb + k0 + kb * 8];
      *(half8*)&L.Bs[kb][n][0] = v;
    }
    __syncthreads();
    int kb = lane >> 4, r = lane & 15;
    half8 af[4], bfv[4];
    #pragma unroll
    for (int mi = 0; mi < 4; mi++) af[mi]  = *(const half8*)&L.As[kb][wm * 64 + mi * 16 + r][0];
    #pragma unroll
    for (int ni = 0; ni < 4; ni++) bfv[ni] = *(const half8*)&L.Bs[kb][wn * 64 + ni * 16 + r][0];
    #pragma unroll
    for (int mi = 0; mi < 4; mi++)
      #pragma unroll
      for (int ni = 0; ni < 4; ni++)
        acc[mi][ni] = __builtin_amdgcn_mfma_f32_16x16x32_f16(af[mi], bfv[ni], acc[mi][ni], 0, 0, 0);
    __syncthreads();
  }

  float radd = (MODE == 1) ? rvec[hz] : 0.f;
  int r = lane & 15, g = lane >> 4;
  #pragma unroll
  for (int mi = 0; mi < 4; mi++) {
    #pragma unroll
    for (int ni = 0; ni < 4; ni++) {
      int col = n0 + wn * 64 + ni * 16 + r;
      if (col >= N) continue;
      float bv = (MODE == 0) ? bias[col] : 0.f;
      if (CT) {
        int row0 = m0 + wm * 64 + mi * 16 + g * 4;
        if (row0 + 3 < M) {
          half4v o;
          #pragma unroll
          for (int j = 0; j < 4; j++) o[j] = (half_t)(acc[mi][ni][j] + bv);
          *(half4v*)&((half_t*)C)[(size_t)col * ldc + row0] = o;
        }
      } else {
        #pragma unroll
        for (int j = 0; j < 4; j++) {
          int row = m0 + wm * 64 + mi * 16 + g * 4 + j;
          if (row >= M) continue;
          float v = acc[mi][ni][j];
          if (MODE == 0)      v += bv;
          else if (MODE == 1) v = frcp(1.f + expf(-(v * INV_SCALE + radd)));
          else if (MODE == 2) v *= INV_SCALE;
          if (ATOM) atomicAdd((float*)&C[(size_t)row * ldc + col], v);
          else      stf(&C[(size_t)row * ldc + col], v);
        }
      }
    }
  }
}

template<int MODE, bool CT, bool ATOM, typename TA, typename TC>
__global__ __launch_bounds__(256)
void mgemm(const TA* __restrict__ A, const half_t* __restrict__ BT,
           TC* __restrict__ C, int M, int N, int Kd,
           int lda, int ldb, int ldc, int hdiv, int kdiv, int kc,
           long long sAb, long long sAh, long long sBb, long long sBh,
           long long sCb, long long sCh,
           const float* __restrict__ bias, const float* __restrict__ rvec)
{
  __shared__ GemmLds L;
  mgemm_body<MODE,CT,ATOM,TA,TC>(L, threadIdx.x, blockIdx.x, blockIdx.y, blockIdx.z,
                                 A, BT, C, M, N, Kd, lda, ldb, ldc, hdiv, kdiv, kc,
                                 sAb, sAh, sBb, sBh, sCb, sCh, bias, rvec);
}

// ---------------------------------------------------------------------------
// qall + kall merged (v3): blocks 0-127 = qall (2048x1024, A fp32),
// blocks 128-1631 = kall (24000x1024, A f16).
// ---------------------------------------------------------------------------
__global__ __launch_bounds__(256)
void qk_fused(const float* __restrict__ query, const half_t* __restrict__ keyh,
              const half_t* __restrict__ wt_q, const half_t* __restrict__ wt_k,
              half_t* __restrict__ qbuf, half_t* __restrict__ kbuf2,
              const float* __restrict__ cb_q, const float* __restrict__ cb_k)
{
  __shared__ GemmLds L;
  int blk = blockIdx.x;
  if (blk < 128) {
    mgemm_body<0,false,false,float,half_t>(L, threadIdx.x, blk & 7, blk >> 3, 0,
        query, wt_q, qbuf, 2048, 1024, 512, 512, 512, 1024, 1, 1, 512,
        0, 0, 0, 0, 0, 0, cb_q, nullptr);
  } else {
    int vb = blk - 128;
    mgemm_body<0,false,false,half_t,half_t>(L, threadIdx.x, vb % 8, vb / 8, 0,
        keyh, wt_k, kbuf2, 24000, 1024, 512, 512, 512, 1024, 1, 1, 512,
        0, 0, 0, 0, 0, 0, cb_k, nullptr);
  }
}

// ---------------------------------------------------------------------------
// FUSED (256 threads, launch_bounds(256,1)) — round-19 structure:
//  blocks 0-31   : cp+alpha scan — 8-deep software-pipelined p prefetch
//  blocks 32-415 : u GEMM (384 virtual blocks), A = q_ca f16
//  blocks 416+   : vT projection (752 blocks), A = keyh f16
// ---------------------------------------------------------------------------
union MidLds { GemmLds g; ScanLds s; };

__global__ __launch_bounds__(256, 1)
void fused_mid(const half_t* __restrict__ p16, float* __restrict__ alpha_slot,
               const half_t* __restrict__ qa, const half_t* __restrict__ kb,
               int lda_u, int ldb_u, long long sAb_u, long long sBb_u,
               float* __restrict__ u_buf,
               const half_t* __restrict__ keyh, const half_t* __restrict__ wt_v,
               half_t* __restrict__ vtbuf, const float* __restrict__ b_value)
{
  __shared__ MidLds lds;
  int blk = blockIdx.x;
  int tid = threadIdx.x;

  if (blk >= 32) {
    if (blk < 416) {                     // ---- u GEMM: vb in [0,384) ----
      int vb = blk - 32;
      int bx = vb % 24; int t = vb / 24;
      int by = t & 1;   int bz = t >> 1;
      mgemm_body<2,false,false,half_t,float>(lds.g, tid, bx, by, bz, qa, kb, u_buf,
          256, 3000, 512, lda_u, ldb_u, 3000, 1, 1, 512,
          sAb_u, 0, sBb_u, 0, 768000, 0, nullptr, nullptr);
    } else {                             // ---- vT proj: vb in [0,752) ----
      int vb = blk - 416;
      int bx = vb & 3; int by = vb >> 2;
      mgemm_body<0,true,false,half_t,half_t>(lds.g, tid, bx, by, 0, keyh, wt_v, vtbuf,
          24000, 512, 512, 512, 512, 24000, 1, 1, 512,
          0, 0, 0, 0, 0, 0, b_value, nullptr);
    }
    return;
  }

  // ---- scan for chain blk: 256 thr x 12 elems (3000 = 250x12) ----
  __builtin_amdgcn_s_setprio(1);
  float (&wsA)[2][4] = lds.s.wsA;
  float (&wsB)[2][4] = lds.s.wsB;
  int lane = tid & 63, wid = tid >> 6;
  int k0 = tid * 12;
  size_t zbase = (size_t)blk * 768000;   // 256*3000
  const half_t* prow = p16 + zbase;

  half4v ph0[3], pb0[3], pb1[3], pb2[3], pb3[3], pb4[3], pb5[3], pb6[3], pb7[3];
  #pragma unroll
  for (int j = 0; j < 3; j++) {
    int k = k0 + j * 4;
    half4v z = {(_Float16)0,(_Float16)0,(_Float16)0,(_Float16)0};
    bool ok = (k + 4 <= 3000);
    ph0[j] = ok ? *(const half4v*)&prow[k]         : z;
    pb0[j] = ok ? *(const half4v*)&prow[3000 + k]  : z;
    pb1[j] = ok ? *(const half4v*)&prow[6000 + k]  : z;
    pb2[j] = ok ? *(const half4v*)&prow[9000 + k]  : z;
    pb3[j] = ok ? *(const half4v*)&prow[12000 + k] : z;
    pb4[j] = ok ? *(const half4v*)&prow[15000 + k] : z;
    pb5[j] = ok ? *(const half4v*)&prow[18000 + k] : z;
    pb6[j] = ok ? *(const half4v*)&prow[21000 + k] : z;
    pb7[j] = ok ? *(const half4v*)&prow[24000 + k] : z;
  }

  float a_prev[12];
  #pragma unroll
  for (int c = 0; c < 12; c++) a_prev[c] = 0.f;
  if (tid == 0) a_prev[0] = 1.f;

  float cpv[12], w[12];
  { // prologue: cp row 0 (multiplicative DPP scan), w = p0*cp0
    float l[12], m = 1.f;
    float p0f[12];
    #pragma unroll
    for (int c = 0; c < 12; c++) {
      p0f[c] = (float)ph0[c >> 2][c & 3];
      l[c] = m;
      m *= fmaxf(1.f - p0f[c], EPSV);
    }
    float incl = wave_iscan_mul(m);
    if (lane == 63) wsA[1][wid] = incl;
    float exclw = incl * frcp(fmaxf(m, 1e-30f));
    block_sync_lds();
    float base = exclw * cross_prod4(&wsA[1][0], wid);
    #pragma unroll
    for (int c = 0; c < 12; c++) { cpv[c] = base * l[c]; w[c] = p0f[c] * cpv[c]; }
  }

#define SCAN_STEP(I, BUF)                                                     \
  {                                                                           \
    int par = (I) & 1;                                                        \
    float t_[12], s2 = 0.f;                                                   \
    _Pragma("unroll")                                                         \
    for (int c = 0; c < 12; c++) {                                            \
      s2 = fmaf(a_prev[c], frcp(fmaxf(cpv[c], EPSV)), s2);                    \
      t_[c] = s2;                                                             \
    }                                                                         \
    float incl2 = wave_iscan_add(s2);                                         \
    if (lane == 63) wsB[par][wid] = incl2;                                    \
    float excl2 = incl2 - s2;                                                 \
    float pnf[12], l_[12], m_ = 1.f;                                          \
    _Pragma("unroll")                                                         \
    for (int c = 0; c < 12; c++) {                                            \
      pnf[c] = (float)BUF[c >> 2][c & 3];                                     \
      l_[c] = m_;                                                             \
      m_ *= fmaxf(1.f - pnf[c], EPSV);                                        \
    }                                                                         \
    float incl1 = wave_iscan_mul(m_);                                         \
    if (lane == 63) wsA[par][wid] = incl1;                                    \
    float excl1 = incl1 * frcp(fmaxf(m_, 1e-30f));                            \
    block_sync_lds();                                                         \
    if ((I) + 9 <= 255) {                                                     \
      const half_t* nrow = prow + (size_t)((I) + 9) * 3000;                   \
      _Pragma("unroll")                                                       \
      for (int j = 0; j < 3; j++) {                                           \
        int k = k0 + j * 4;                                                   \
        if (k + 4 <= 3000) BUF[j] = *(const half4v*)&nrow[k];                 \
      }                                                                       \
    }                                                                         \
    __builtin_amdgcn_sched_barrier(0);                                        \
    float off = excl2 + cross_sum4(&wsB[par][0], wid);                        \
    size_t rbase = zbase + (size_t)(I) * 3000;                                \
    _Pragma("unroll")                                                         \
    for (int q4 = 0; q4 < 3; q4++) {                                          \
      f32x4 o;                                                                \
      _Pragma("unroll")                                                       \
      for (int j = 0; j < 4; j++) {                                           \
        int c = q4 * 4 + j;                                                   \
        float an = w[c] * (off + t_[c]);                                      \
        a_prev[c] = an;                                                       \
        o[j] = an;                                                            \
      }                                                                       \
      int k = k0 + q4 * 4;                                                    \
      if (k + 4 <= 3000) *(f32x4*)&alpha_slot[rbase + k] = o;                 \
    }                                                                         \
    float base1 = excl1 * cross_prod4(&wsA[par][0], wid);                     \
    _Pragma("unroll")                                                         \
    for (int c = 0; c < 12; c++) { cpv[c] = base1 * l_[c]; w[c] = pnf[c] * cpv[c]; } \
  }

  for (int i = 0; i < 256; i += 8) {
    SCAN_STEP(i,     pb0);
    SCAN_STEP(i + 1, pb1);
    SCAN_STEP(i + 2, pb2);
    SCAN_STEP(i + 3, pb3);
    SCAN_STEP(i + 4, pb4);
    SCAN_STEP(i + 5, pb5);
    SCAN_STEP(i + 6, pb6);
    SCAN_STEP(i + 7, pb7);
  }
#undef SCAN_STEP
}

// ---------------------------------------------------------------------------
// Chunkwise beta — sliding-window form (round 19, unchanged).
// ---------------------------------------------------------------------------
__global__ __launch_bounds__(256)
void beta_kernel(const float* __restrict__ ubuf, const float* __restrict__ alpha_slot,
                 float* __restrict__ beta_slot)
{
  __shared__ __align__(16) float se[3008];
  __shared__ __align__(16) float dn[3008];
  __shared__ __align__(16) float tt[3040];
  __shared__ float red[4];
  int bq = blockIdx.x;
  int b = bq >> 8, q = bq & 255;
  int tid = threadIdx.x;
  int lane = tid & 63, wid = tid >> 6;
  int k0 = tid * 12;
  bool act = (k0 < 3000);
  const float* urow = ubuf + (size_t)bq * 3000;
  float lmax = -3.0e38f;
  for (int c = tid; c < 750; c += 256) {
    f32x4 v = *(const f32x4*)&urow[c * 4];
    *(f32x4*)&se[c * 4] = v;
    lmax = fmaxf(lmax, fmaxf(fmaxf(v[0], v[1]), fmaxf(v[2], v[3])));
  }
  #pragma unroll
  for (int d = 32; d > 0; d >>= 1) lmax = fmaxf(lmax, __shfl_xor(lmax, d));
  if (lane == 0) red[wid] = lmax;
  __syncthreads();
  float umax = fmaxf(fmaxf(red[0], red[1]), fmaxf(red[2], red[3]));
  for (int c = tid; c < 750; c += 256) {
    f32x4 v = *(const f32x4*)&se[c * 4];
    #pragma unroll
    for (int j = 0; j < 4; j++) v[j] = fmaxf(expf(v[j] - umax), 1e-5f);
    *(f32x4*)&se[c * 4] = v;
  }
  if (tid < 40) tt[3000 + tid] = 0.f;
  __syncthreads();
  if (act) {
    float sb[27];
    #pragma unroll
    for (int j = 0; j < 27; j++) {
      int idx = k0 - 15 + j;
      sb[j] = (idx >= 0) ? se[idx] : 0.f;
    }
    float wsum = 0.f;
    #pragma unroll
    for (int j = 0; j < 16; j++) wsum += sb[j];
    dn[k0] = wsum;
    #pragma unroll
    for (int j = 1; j < 12; j++) {
      wsum += sb[15 + j] - sb[j - 1];
      dn[k0 + j] = wsum;
    }
  }
  __syncthreads();
  for (int h = 0; h < 4; h++) {
    const float* arow = alpha_slot + ((size_t)((b * 4 + h) * 256 + q)) * 3000;
    for (int c = tid; c < 750; c += 256) {
      f32x4 a = *(const f32x4*)&arow[c * 4];
      f32x4 d = *(const f32x4*)&dn[c * 4];
      f32x4 o;
      #pragma unroll
      for (int j = 0; j < 4; j++) o[j] = a[j] * frcp(d[j]);
      *(f32x4*)&tt[c * 4] = o;
    }
    __syncthreads();
    float* brow = beta_slot + ((size_t)((b * 4 + h) * 256 + q)) * 3000;
    if (act) {
      float tb[28];
      #pragma unroll
      for (int j = 0; j < 28; j++) tb[j] = tt[k0 + j];
      float wv = 0.f;
      #pragma unroll
      for (int j = 0; j < 16; j++) wv += tb[j];
      float outv[12];
      outv[0] = se[k0] * wv;
      #pragma unroll
      for (int j = 1; j < 12; j++) {
        wv += tb[15 + j] - tb[j - 1];
        outv[j] = se[k0 + j] * wv;
      }
      #pragma unroll
      for (int q4 = 0; q4 < 3; q4++) {
        f32x4 o;
        #pragma unroll
        for (int j = 0; j < 4; j++) o[j] = outv[q4 * 4 + j];
        *(f32x4*)&brow[k0 + q4 * 4] = o;
      }
    }
    __syncthreads();
  }
}

// ---------------------------------------------------------------------------
extern "C" void kernel_launch(void* const* d_in, const int* in_sizes, int n_in,
                              void* d_out, int out_size, void* d_ws, size_t ws_size,
                              hipStream_t stream)
{
  const float* key        = (const float*)d_in[0];
  const float* query      = (const float*)d_in[1];
  const float* w_key_ma   = (const float*)d_in[2];
  const float* b_key_ma   = (const float*)d_in[3];
  const float* w_query_ma = (const float*)d_in[4];
  const float* b_query_ma = (const float*)d_in[5];
  const float* rvec       = (const float*)d_in[6];
  const float* w_key_ca   = (const float*)d_in[7];
  const float* b_key_ca   = (const float*)d_in[8];
  const float* w_query_ca = (const float*)d_in[9];
  const float* b_query_ca = (const float*)d_in[10];
  const float* w_value    = (const float*)d_in[11];
  const float* b_value    = (const float*)d_in[12];

  // Outputs FP32: cv | alpha | beta, flat.
  float* out       = (float*)d_out;
  float* cv_out    = out;                                  // (8,256,512)
  float* alpha_out = out + (size_t)1048576;                // (8,4,256,3000)
  float* beta_out  = alpha_out + (size_t)24576000;         // (8,4,256,3000)
  half_t* p16      = (half_t*)beta_out;                    // p_choose fp16 (first half)
  half_t* keyh     = (half_t*)(beta_out + 12288000);       // key f16 (second half; dead before beta)

  dim3 blk(256);
  bool v3 = ws_size >= (size_t)109322240;

  if (v3) {
    // v3 layout: kbuf2[24000][1024] f16 | qbuf[2048][1024] f16 | u f32 | vtbuf | wts | catbias
    half_t* kbuf2 = (half_t*)d_ws;
    half_t* qbuf  = (half_t*)((char*)d_ws + 49152000);
    float*  u_buf = (float*)((char*)d_ws + 57540608);
    half_t* vtbuf = (half_t*)((char*)d_ws + 82116608);
    half_t* wt_q  = (half_t*)((char*)d_ws + 106692608);   // [1024][512]
    half_t* wt_k  = (half_t*)((char*)d_ws + 107741184);   // [1024][512]
    half_t* wt_v  = (half_t*)((char*)d_ws + 108789760);
    float*  cb_q  = (float*)((char*)d_ws + 109314048);
    float*  cb_k  = (float*)((char*)d_ws + 109318144);

    prep<<<dim3(14305), blk, 0, stream>>>(
        w_query_ma, wt_q, w_query_ca, wt_q + 262144,
        w_key_ma,   wt_k, w_key_ca,   wt_k + 262144,
        w_value,    wt_v, key, keyh,
        b_query_ma, b_query_ca, b_key_ma, b_key_ca, cb_q, cb_k,
        cv_out);

    qk_fused<<<dim3(1632), blk, 0, stream>>>(query, keyh, wt_q, wt_k, qbuf, kbuf2, cb_q, cb_k);

    // e_ma -> p16 (A = q_ma cols of qbuf f16)
    mgemm<1,false,false,half_t,half_t><<<dim3(24,2,32), blk, 0, stream>>>(qbuf, kbuf2, p16, 256,3000, 128, 1024,1024,3000, 4,1,128,
        262144,128, 3072000,128, 3072000,768000, nullptr, rvec);

    // FUSED: scan (0-31) + u GEMM (32-415) + vT shells (416-1167)
    fused_mid<<<dim3(1168), blk, 0, stream>>>(p16, alpha_out,
        qbuf + 512, kbuf2 + 512, 1024, 1024, 262144, 3072000,
        u_buf, keyh, wt_v, vtbuf, b_value);

    beta_kernel<<<dim3(2048), blk, 0, stream>>>(u_buf, alpha_out, beta_out);

    mgemm<3,false,true,float,float><<<dim3(1,2,256), blk, 0, stream>>>(beta_out, vtbuf, cv_out, 256,128,3000, 3000,24000,512, 4,8,384,
        3072000,768000, 3000,3072000, 131072,128, nullptr, nullptr);
  } else {
    // v1 fallback: kbuf | qbuf | u | 5x wt. 55.97MB.
    if (ws_size < (size_t)55967744) return;
    half_t* kbuf   = (half_t*)d_ws;
    half_t* qbuf   = (half_t*)((char*)d_ws + 24576000);
    float*  u_buf  = (float*)((char*)d_ws + 28770304);
    half_t* wt_qma = (half_t*)((char*)d_ws + 53346304);
    half_t* wt_kma = (half_t*)((char*)d_ws + 53870592);
    half_t* wt_qca = (half_t*)((char*)d_ws + 54394880);
    half_t* wt_kca = (half_t*)((char*)d_ws + 54919168);
    half_t* wt_v   = (half_t*)((char*)d_ws + 55443456);

    prep<<<dim3(14305), blk, 0, stream>>>(
        w_query_ma, wt_qma, w_query_ca, wt_qca,
        w_key_ma,   wt_kma, w_key_ca,   wt_kca,
        w_value,    wt_v, key, keyh,
        nullptr, nullptr, nullptr, nullptr, nullptr, nullptr,
        cv_out);

    mgemm<0,false,false,float ,half_t><<<dim3(4,16,1),  blk, 0, stream>>>(query, wt_qma, qbuf, 2048, 512, 512, 512,512,512, 1,1,512, 0,0,0,0,0,0, b_query_ma, nullptr);
    mgemm<0,false,false,half_t,half_t><<<dim3(4,188,1), blk, 0, stream>>>(keyh,  wt_kma, kbuf, 24000,512, 512, 512,512,512, 1,1,512, 0,0,0,0,0,0, b_key_ma,   nullptr);
    mgemm<1,false,false,half_t,half_t><<<dim3(24,2,32), blk, 0, stream>>>(qbuf,  kbuf, p16, 256,3000, 128, 512,512,3000, 4,1,128,
        131072,128, 1536000,128, 3072000,768000, nullptr, rvec);

    mgemm<0,false,false,float ,half_t><<<dim3(4,16,1),  blk, 0, stream>>>(query, wt_qca, qbuf, 2048, 512, 512, 512,512,512, 1,1,512, 0,0,0,0,0,0, b_query_ca, nullptr);
    mgemm<0,false,false,half_t,half_t><<<dim3(4,188,1), blk, 0, stream>>>(keyh,  wt_kca, kbuf, 24000,512, 512, 512,512,512, 1,1,512, 0,0,0,0,0,0, b_key_ca,   nullptr);

    // FUSED: scan (0-31) + u GEMM (32-415); vT serial after (into kbuf)
    fused_mid<<<dim3(416), blk, 0, stream>>>(p16, alpha_out,
        qbuf, kbuf, 512, 512, 131072, 1536000,
        u_buf, keyh, wt_v, kbuf, b_value);

    mgemm<0,true,false,half_t,half_t><<<dim3(4,188,1), blk, 0, stream>>>(keyh, wt_v, kbuf, 24000,512, 512, 512,512,24000, 1,1,512, 0,0,0,0,0,0, b_value, nullptr);

    beta_kernel<<<dim3(2048), blk, 0, stream>>>(u_buf, alpha_out, beta_out);

    mgemm<3,false,true,float,float><<<dim3(1,2,256), blk, 0, stream>>>(beta_out, kbuf, cv_out, 256,128,3000, 3000,24000,512, 4,8,384,
        3072000,768000, 3000,3072000, 131072,128, nullptr, nullptr);
  }
}